// Round 2
// baseline (533.785 us; speedup 1.0000x reference)
//
#include <hip/hip_runtime.h>

// WindowAttention: B=256 windows, N=256 tokens, C=384, 12 heads, d=32.
// K0 cast weights->bf16 | K1 transpose-cast x (B,C,N)f32 -> xt (B*N,C)bf16
// K2 per-(b,h), 512 thr: qkv MFMA GEMM + l2norm + pipelined MFMA attention -> xa bf16
// K3 proj GEMM (32x32x16 MFMA, 128B coalesced f32 stores) -> (B,C,N) f32
// 16x16x32 layouts: A/B: row=lane&15, k=(lane>>4)*8+j ; D: col=lane&15, row=(lane>>4)*4+r
// 32x32x16 layouts: A/B: row=lane&31, k=(lane>>5)*8+j ; D: col=lane&31, row=(reg&3)+8*(reg>>2)+4*(lane>>5)
// LDS tensors stored fragment-ordered [k-group][row][8] -> all ds_read_b128 2-way (free).

#define DIM 384
#define NT 256
#define NH 12
#define HD 32
#define SCALE 0.17677669529663687f

typedef __bf16 bf16;
typedef __bf16 bf16x8 __attribute__((ext_vector_type(8)));
typedef float f32x4 __attribute__((ext_vector_type(4)));
typedef float f32x16 __attribute__((ext_vector_type(16)));

#define MFMA16(a, b, c) __builtin_amdgcn_mfma_f32_16x16x32_bf16(a, b, c, 0, 0, 0)
#define MFMA32(a, b, c) __builtin_amdgcn_mfma_f32_32x32x16_bf16(a, b, c, 0, 0, 0)

// ---------------- K0: cast weights to bf16 ----------------
__global__ void k_cast_w(const float* __restrict__ qkv_w, const float* __restrict__ proj_w,
                         bf16* __restrict__ wq, bf16* __restrict__ wp) {
    int i = blockIdx.x * 256 + threadIdx.x;
    if (i < 3 * DIM * DIM) wq[i] = (bf16)qkv_w[i];
    if (i < DIM * DIM)     wp[i] = (bf16)proj_w[i];
}

// ---------------- K1: x (B,C,N) f32 -> xt (B*N, C) bf16. 64x64 tiles, full-line I/O ----
__global__ void k_transpose_cast(const float* __restrict__ x, bf16* __restrict__ xt) {
    __shared__ float tile[64][65];
    const int b = blockIdx.z, c0 = blockIdx.y * 64, n0 = blockIdx.x * 64;
    const int tx = threadIdx.x & 63, ty = threadIdx.x >> 6;  // ty 0..3
    const float* xp = x + (size_t)b * DIM * NT;
#pragma unroll
    for (int i = 0; i < 16; ++i) {
        int c = ty + i * 4;
        tile[c][tx] = xp[(size_t)(c0 + c) * NT + n0 + tx];  // 256B/row read
    }
    __syncthreads();
    bf16* op = xt + (size_t)b * NT * DIM;
#pragma unroll
    for (int i = 0; i < 16; ++i) {
        int n = ty + i * 4;
        op[(size_t)(n0 + n) * DIM + c0 + tx] = (bf16)tile[tx][n];  // 128B/row write
    }
}

// ---------------- K2: fused qkv GEMM + l2norm + attention, one block per (b,h) ----------------
__launch_bounds__(512, 4)
__global__ void k_qkv_attn(const bf16* __restrict__ xt, const bf16* __restrict__ wq,
                           const float* __restrict__ qkv_b, bf16* __restrict__ attn_out) {
    // 16384*3 + 8192 = 57344 B -> 2 blocks/CU (16 waves)
    __shared__ bf16 qp[4][NT][8];     // [kgrp][token][e]: q element kgrp*8+e
    __shared__ bf16 kp[4][NT][8];
    __shared__ bf16 vp[32][32][8];    // [keygrp][d][e]: V[key=g*8+e][d]
    __shared__ bf16 pp[8][4][16][8];  // per-wave P: [w][keygrp][query][e]

    const int h = blockIdx.x, b = blockIdx.y;
    const int tid = threadIdx.x;
    const int lane = tid & 63, w = tid >> 6;      // 8 waves
    const int l15 = lane & 15, quad = lane >> 4;
    const f32x4 zf = {0.f, 0.f, 0.f, 0.f};

    // ---- Phase A: qkv GEMM. Wave w owns tokens [w*32, w*32+32), all 96 outputs.
    f32x4 acc[6][2];
#pragma unroll
    for (int jt = 0; jt < 6; ++jt)
#pragma unroll
        for (int tt = 0; tt < 2; ++tt) acc[jt][tt] = zf;

    const bf16* xrow[2];
#pragma unroll
    for (int tt = 0; tt < 2; ++tt) {
        int tok = w * 32 + tt * 16 + l15;
        xrow[tt] = xt + (size_t)(b * NT + tok) * DIM + quad * 8;
    }
    const bf16* wrow[6];
#pragma unroll
    for (int jt = 0; jt < 6; ++jt) {
        int jj = jt * 16 + l15;
        wrow[jt] = wq + (size_t)((jj >> 5) * DIM + h * HD + (jj & 31)) * DIM + quad * 8;
    }

#pragma unroll 2
    for (int kc = 0; kc < 12; ++kc) {
        int k0 = kc * 32;
        bf16x8 bfr[2], afr[6];
#pragma unroll
        for (int tt = 0; tt < 2; ++tt) bfr[tt] = *(const bf16x8*)(xrow[tt] + k0);
#pragma unroll
        for (int jt = 0; jt < 6; ++jt) afr[jt] = *(const bf16x8*)(wrow[jt] + k0);
#pragma unroll
        for (int jt = 0; jt < 6; ++jt)
#pragma unroll
            for (int tt = 0; tt < 2; ++tt)
                acc[jt][tt] = MFMA16(afr[jt], bfr[tt], acc[jt][tt]);
    }

    // ---- epilogue: +bias, l2-normalize q,k, scatter to fragment-order LDS ----
    float bias[6][4];
#pragma unroll
    for (int jt = 0; jt < 6; ++jt)
#pragma unroll
        for (int r = 0; r < 4; ++r) {
            int j = jt * 16 + quad * 4 + r;
            bias[jt][r] = qkv_b[(j >> 5) * DIM + h * HD + (j & 31)];
        }
#pragma unroll
    for (int tt = 0; tt < 2; ++tt) {
        int tok = w * 32 + tt * 16 + l15;  // = D col
        float sq = 0.f, sk = 0.f;
#pragma unroll
        for (int jt = 0; jt < 6; ++jt)
#pragma unroll
            for (int r = 0; r < 4; ++r) {
                float t = acc[jt][tt][r] + bias[jt][r];
                acc[jt][tt][r] = t;
                if (jt < 2) sq += t * t;
                else if (jt < 4) sk += t * t;
            }
        sq += __shfl_xor(sq, 16); sq += __shfl_xor(sq, 32);
        sk += __shfl_xor(sk, 16); sk += __shfl_xor(sk, 32);
        float iq = 1.f / fmaxf(sqrtf(sq), 1e-12f);
        float ik = 1.f / fmaxf(sqrtf(sk), 1e-12f);
#pragma unroll
        for (int jt = 0; jt < 6; ++jt)
#pragma unroll
            for (int r = 0; r < 4; ++r) {
                int j = jt * 16 + quad * 4 + r;  // D row
                float t = acc[jt][tt][r];
                if (j < 32)      qp[j >> 3][tok][j & 7] = (bf16)(t * iq);
                else if (j < 64) { int j2 = j - 32; kp[j2 >> 3][tok][j2 & 7] = (bf16)(t * ik); }
                else             { int d = j - 64; vp[tok >> 3][d][tok & 7] = (bf16)t; }
            }
    }
    __syncthreads();

    // ---- Phase C: attention. Wave w owns queries [w*32, w*32+32). Pipelined kt loop.
#pragma unroll 1
    for (int qt = 0; qt < 2; ++qt) {
        const int nq0 = w * 32 + qt * 16;
        bf16x8 qa = *(const bf16x8*)&qp[quad][nq0 + l15][0];
        f32x4 o0 = zf, o1 = zf;
        float dsum = 0.f;
        bf16x8 pa, vb0, vb1;

        // S^T block: MFMA(k,q) -> lane holds P[query=l15][key=nk0+quad*4+r]
        auto sblock = [&](int kt) {
#pragma unroll
            for (int st = 0; st < 2; ++st) {
                int nk0 = kt * 32 + st * 16;
                bf16x8 ka = *(const bf16x8*)&kp[quad][nk0 + l15][0];
                f32x4 s = MFMA16(ka, qa, zf);
#pragma unroll
                for (int r = 0; r < 4; ++r) {
                    float p = __expf(s[r] * SCALE);  // |logit|<=0.178: no max-sub needed
                    dsum += p;
                    pp[w][st * 2 + (quad >> 1)][l15][(quad & 1) * 4 + r] = (bf16)p;
                }
            }
        };
        auto rblock = [&](int kt) {
            pa  = *(const bf16x8*)&pp[w][quad][l15][0];
            vb0 = *(const bf16x8*)&vp[kt * 4 + quad][l15][0];
            vb1 = *(const bf16x8*)&vp[kt * 4 + quad][16 + l15][0];
        };

        sblock(0);
        rblock(0);
#pragma unroll
        for (int kt = 0; kt < 8; ++kt) {
            bf16x8 cpa = pa, cv0 = vb0, cv1 = vb1;
            if (kt < 7) { sblock(kt + 1); rblock(kt + 1); }  // fills latency of reads(kt)
            o0 = MFMA16(cpa, cv0, o0);
            o1 = MFMA16(cpa, cv1, o1);
        }

        dsum += __shfl_xor(dsum, 16);
        dsum += __shfl_xor(dsum, 32);  // full denom for query nq0+l15, all quads
        bf16* op = attn_out + (size_t)(b * NT) * DIM + h * HD;
#pragma unroll
        for (int r = 0; r < 4; ++r) {
            int ql = quad * 4 + r;              // O row = query local
            float inv = 1.f / __shfl(dsum, ql); // denom lives at lane l15=ql
            size_t ro = (size_t)(nq0 + ql) * DIM;
            op[ro + l15]      = (bf16)(o0[r] * inv);
            op[ro + 16 + l15] = (bf16)(o1[r] * inv);
        }
    }
}

// ---------------- K3: proj GEMM (32x32x16) + transposed f32 output, 128B stores ----------------
__launch_bounds__(256, 4)
__global__ void k_proj(const bf16* __restrict__ xa, const bf16* __restrict__ wp,
                       const float* __restrict__ proj_b, float* __restrict__ out) {
    const int cb = blockIdx.x, nb = blockIdx.y, b = blockIdx.z;
    const int tid = threadIdx.x, lane = tid & 63, w = tid >> 6;
    const int wc = w & 1, wn = w >> 1;           // wave tile: 64c x 64n
    const int l31 = lane & 31, half = lane >> 5;

    f32x16 acc[2][2];
#pragma unroll
    for (int i = 0; i < 2; ++i)
#pragma unroll
        for (int j = 0; j < 2; ++j)
#pragma unroll
            for (int r = 0; r < 16; ++r) acc[i][j][r] = 0.f;

    const bf16* ar[2];
    const bf16* br[2];
#pragma unroll
    for (int ct = 0; ct < 2; ++ct)
        ar[ct] = wp + (size_t)(cb * 128 + wc * 64 + ct * 32 + l31) * DIM + half * 8;
#pragma unroll
    for (int nt = 0; nt < 2; ++nt)
        br[nt] = xa + (size_t)(b * NT + nb * 128 + wn * 64 + nt * 32 + l31) * DIM + half * 8;

#pragma unroll 2
    for (int kc = 0; kc < 24; ++kc) {
        int k0 = kc * 16;
        bf16x8 a0 = *(const bf16x8*)(ar[0] + k0);
        bf16x8 a1 = *(const bf16x8*)(ar[1] + k0);
        bf16x8 b0 = *(const bf16x8*)(br[0] + k0);
        bf16x8 b1 = *(const bf16x8*)(br[1] + k0);
        acc[0][0] = MFMA32(a0, b0, acc[0][0]);
        acc[0][1] = MFMA32(a0, b1, acc[0][1]);
        acc[1][0] = MFMA32(a1, b0, acc[1][0]);
        acc[1][1] = MFMA32(a1, b1, acc[1][1]);
    }

    float* op = out + (size_t)b * DIM * NT;  // out[b][c][n]
#pragma unroll
    for (int ct = 0; ct < 2; ++ct)
#pragma unroll
        for (int reg = 0; reg < 16; ++reg) {
            int row = (reg & 3) + 8 * (reg >> 2) + 4 * half;
            int c = cb * 128 + wc * 64 + ct * 32 + row;
            float bias = proj_b[c];
#pragma unroll
            for (int nt = 0; nt < 2; ++nt) {
                int n = nb * 128 + wn * 64 + nt * 32 + l31;  // 32 lanes = 128B line
                op[(size_t)c * NT + n] = acc[ct][nt][reg] + bias;
            }
        }
}

extern "C" void kernel_launch(void* const* d_in, const int* in_sizes, int n_in,
                              void* d_out, int out_size, void* d_ws, size_t ws_size,
                              hipStream_t stream) {
    const float* x      = (const float*)d_in[0];
    const float* qkv_w  = (const float*)d_in[1];
    const float* qkv_b  = (const float*)d_in[2];
    const float* proj_w = (const float*)d_in[3];
    const float* proj_b = (const float*)d_in[4];
    float* out = (float*)d_out;

    char* ws = (char*)d_ws;
    bf16* xt = (bf16*)ws;                    // 50,331,648 B
    bf16* xa = (bf16*)(ws + 50331648);       // 50,331,648 B
    bf16* wq = (bf16*)(ws + 100663296);      // 884,736 B
    bf16* wp = (bf16*)(ws + 101548032);      // 294,912 B

    k_cast_w<<<dim3(1728), dim3(256), 0, stream>>>(qkv_w, proj_w, wq, wp);
    k_transpose_cast<<<dim3(4, 6, 256), dim3(256), 0, stream>>>(x, xt);
    k_qkv_attn<<<dim3(NH, 256), dim3(512), 0, stream>>>(xt, wq, qkv_b, xa);
    k_proj<<<dim3(3, 2, 256), dim3(256), 0, stream>>>(xa, wp, proj_b, out);
}